// Round 3
// baseline (309.780 us; speedup 1.0000x reference)
//
#include <hip/hip_runtime.h>

#define SCALE 0.17677669529663687f

typedef __attribute__((ext_vector_type(8))) short bf16x8;
typedef __attribute__((ext_vector_type(4))) float f32x4;

__device__ __forceinline__ unsigned short f2bf(float f) {
    unsigned u = __float_as_uint(f);
    u += 0x7FFFu + ((u >> 16) & 1u);   // round-to-nearest-even
    return (unsigned short)(u >> 16);
}
__device__ __forceinline__ float bf2f(unsigned short s) {
    return __uint_as_float(((unsigned)s) << 16);
}

// ---------------- weights -> bf16 ----------------
__global__ __launch_bounds__(256) void wconv_kernel(
        const float* __restrict__ w_qkv, const float* __restrict__ w_out,
        unsigned short* __restrict__ wq, unsigned short* __restrict__ wo) {
    int idx = blockIdx.x * 256 + threadIdx.x;
    if (idx < 196608) wq[idx] = f2bf(w_qkv[idx]);
    else if (idx < 262144) wo[idx - 196608] = f2bf(w_out[idx - 196608]);
}

// ================= PATH A (split) =================

// ---- k1a: QKV GEMM. block = 64 consecutive tokens, 512 threads (8 waves).
// LDS: [0,32768) A: 64 tok x 256 ch bf16 swizzled; [32768,65536) D bounce (64 x 256 bf16)
__global__ __launch_bounds__(512, 4) void qkv_gemm_kernel(
        const float* __restrict__ x, const unsigned short* __restrict__ wq,
        unsigned short* __restrict__ qkv_ws) {
    __shared__ unsigned char lds[65536];
    const int tid = threadIdx.x;
    const int tb  = blockIdx.x << 6;       // token base (64 consecutive w positions)
    const int b   = tb >> 14;
    const int hw  = tb & 16383;
    const float* xb = x + (size_t)b * 4194304 + hw;

    // stage A: per ch, 64 contiguous floats (16 float4). 4096 chunks / 512 thr = 8 each.
    #pragma unroll
    for (int it = 0; it < 8; ++it) {
        int idx = it * 512 + tid;
        int c = idx >> 4, q4 = idx & 15;
        float4 v = *(const float4*)(xb + (size_t)c * 16384 + q4 * 4);
        #pragma unroll
        for (int j = 0; j < 4; ++j) {
            int t = q4 * 4 + j;
            int slot = (c >> 3) ^ (t & 7);
            float f = (j == 0) ? v.x : (j == 1) ? v.y : (j == 2) ? v.z : v.w;
            *(unsigned short*)(lds + t * 512 + (slot << 4) + (c & 7) * 2) = f2bf(f);
        }
    }
    __syncthreads();

    const int lane = tid & 63, wave = tid >> 6;
    const int lrow = lane & 15, lk = lane >> 4;
    const int j0w = wave * 32;             // wave's 32-col slice within each 256-col pass

    for (int nb = 0; nb < 3; ++nb) {
        f32x4 acc[4][2];
        #pragma unroll
        for (int mt = 0; mt < 4; ++mt)
            #pragma unroll
            for (int nt = 0; nt < 2; ++nt)
                acc[mt][nt] = (f32x4){0.f, 0.f, 0.f, 0.f};
        #pragma unroll
        for (int k = 0; k < 8; ++k) {
            bf16x8 a[4], bb[2];
            #pragma unroll
            for (int mt = 0; mt < 4; ++mt) {
                int t = mt * 16 + lrow;
                int slot = (k * 4 + lk) ^ (t & 7);
                a[mt] = *(const bf16x8*)(lds + t * 512 + (slot << 4));
            }
            #pragma unroll
            for (int nt = 0; nt < 2; ++nt) {
                int j = nb * 256 + j0w + nt * 16 + lrow;
                bb[nt] = *(const bf16x8*)((const unsigned char*)wq + (size_t)j * 512 + k * 64 + lk * 16);
            }
            #pragma unroll
            for (int mt = 0; mt < 4; ++mt)
                #pragma unroll
                for (int nt = 0; nt < 2; ++nt)
                    acc[mt][nt] = __builtin_amdgcn_mfma_f32_16x16x32_bf16(a[mt], bb[nt], acc[mt][nt], 0, 0, 0);
        }
        // D-frags -> D-bounce LDS (bf16, swizzled). col=lane&15, row=lk*4+i
        #pragma unroll
        for (int mt = 0; mt < 4; ++mt)
            #pragma unroll
            for (int nt = 0; nt < 2; ++nt)
                #pragma unroll
                for (int i = 0; i < 4; ++i) {
                    int t = mt * 16 + lk * 4 + i;
                    int ch = j0w + nt * 16 + lrow;
                    int slot = (ch >> 3) ^ (t & 7);
                    *(unsigned short*)(lds + 32768 + t * 512 + (slot << 4) + (ch & 7) * 2) = f2bf(acc[mt][nt][i]);
                }
        __syncthreads();
        // coop store: qkv_ws[token][nb*256 + ch], coalesced b128
        #pragma unroll
        for (int it = 0; it < 4; ++it) {
            int idx = it * 512 + tid;
            int t = idx >> 5, c = idx & 31;
            int slot = c ^ (t & 7);
            bf16x8 vch = *(const bf16x8*)(lds + 32768 + t * 512 + (slot << 4));
            *(bf16x8*)(qkv_ws + (size_t)(tb + t) * 768 + nb * 256 + c * 8) = vch;
        }
        __syncthreads();
    }
}

// ---- k1b: head-attention. block = 32 consecutive tokens, 512 threads.
// LDS 48KB: 32 tokens x 768 ch bf16, swizzled (row stride 1536B, 96 slots of 16B)
__global__ __launch_bounds__(512, 6) void attn_kernel(
        const unsigned short* __restrict__ qkv_ws, unsigned short* __restrict__ o_ws) {
    __shared__ unsigned char lds[49152];
    const int tid = threadIdx.x;
    const int tb  = blockIdx.x << 5;

    {
        const int t = tid >> 4, cpart = tid & 15;
        const unsigned short* src = qkv_ws + (size_t)(tb + t) * 768;
        #pragma unroll
        for (int ci = 0; ci < 6; ++ci) {
            int c = ci * 16 + cpart;       // 16B chunk index 0..95
            *(bf16x8*)(lds + t * 1536 + ((c ^ (t & 7)) << 4)) = *(const bf16x8*)(src + c * 8);
        }
    }
    __syncthreads();

    const int t  = tid >> 4;
    const int h  = (tid >> 1) & 7;
    const int hf = tid & 1;
    const int tx = t & 7;
    const unsigned char* row = lds + t * 1536;
    float q[16];
    #pragma unroll
    for (int jj = 0; jj < 2; ++jj) {
        int slot = (h * 4 + hf * 2 + jj) ^ tx;
        bf16x8 v = *(const bf16x8*)(row + (slot << 4));
        #pragma unroll
        for (int e = 0; e < 8; ++e) q[jj * 8 + e] = bf2f((unsigned short)v[e]);
    }
    float dots[8];
    #pragma unroll
    for (int g = 0; g < 8; ++g) {
        float acc = 0.f;
        #pragma unroll
        for (int jj = 0; jj < 2; ++jj) {
            int slot = (32 + g * 4 + hf * 2 + jj) ^ tx;
            bf16x8 v = *(const bf16x8*)(row + (slot << 4));
            #pragma unroll
            for (int e = 0; e < 8; ++e) acc += q[jj * 8 + e] * bf2f((unsigned short)v[e]);
        }
        dots[g] = acc;
    }
    #pragma unroll
    for (int g = 0; g < 8; ++g)
        dots[g] = (dots[g] + __shfl_xor(dots[g], 1, 64)) * SCALE;
    float mx = dots[0];
    #pragma unroll
    for (int g = 1; g < 8; ++g) mx = fmaxf(mx, dots[g]);
    float sum = 0.f;
    #pragma unroll
    for (int g = 0; g < 8; ++g) { dots[g] = __expf(dots[g] - mx); sum += dots[g]; }
    float inv = 1.f / sum;
    float o[16];
    #pragma unroll
    for (int d = 0; d < 16; ++d) o[d] = 0.f;
    #pragma unroll
    for (int g = 0; g < 8; ++g) {
        float p = dots[g] * inv;
        #pragma unroll
        for (int jj = 0; jj < 2; ++jj) {
            int slot = (64 + g * 4 + hf * 2 + jj) ^ tx;
            bf16x8 v = *(const bf16x8*)(row + (slot << 4));
            #pragma unroll
            for (int e = 0; e < 8; ++e) o[jj * 8 + e] += p * bf2f((unsigned short)v[e]);
        }
    }
    // mixing fold: out2[win][n'=h*8+r][c'=s*32+d], d = hf*16 + jj*8 + e
    const int tok = tb + t;
    const int bb2 = tok >> 14, rem = tok & 16383;
    const int himg = rem >> 7, wimg = rem & 127;
    const int ih = himg >> 3, r = himg & 7;
    const int iw = wimg >> 3, s = wimg & 7;
    const int win = (bb2 << 8) + (ih << 4) + iw;
    unsigned short* dst = o_ws + ((size_t)win * 64 + h * 8 + r) * 256 + s * 32 + hf * 16;
    #pragma unroll
    for (int jj = 0; jj < 2; ++jj) {
        bf16x8 pk;
        #pragma unroll
        for (int e = 0; e < 8; ++e) pk[e] = (short)f2bf(o[jj * 8 + e]);
        *(bf16x8*)(dst + jj * 8) = pk;
    }
}

// ---- k2: out-projection + bias + output scatter (32KB LDS, two y half-passes)
__global__ __launch_bounds__(512, 6) void outproj_kernel(
        const unsigned short* __restrict__ o_ws, const unsigned short* __restrict__ wo,
        const float* __restrict__ b_out, float* __restrict__ out) {
    __shared__ unsigned char lds[32768];
    const int tid = threadIdx.x;
    const int bid = blockIdx.x;
    const int b  = bid >> 8;
    const int ih = (bid >> 4) & 15;
    const int iw = bid & 15;

    {
        const unsigned char* src = (const unsigned char*)(o_ws + (size_t)bid * 16384);
        #pragma unroll
        for (int it = 0; it < 4; ++it) {
            int q = it * 512 + tid;            // 16-byte chunk id, 2048 total
            int np = q >> 5;                   // row n'
            int slot = (q & 31) ^ (np & 7);
            *(bf16x8*)(lds + np * 512 + (slot << 4)) = *(const bf16x8*)(src + q * 16);
        }
    }
    __syncthreads();

    const int lane = tid & 63;
    const int wave = tid >> 6;
    const int lrow = lane & 15;
    const int lk   = lane >> 4;
    const int j0 = wave * 32;

    f32x4 acc[4][2];
    #pragma unroll
    for (int mt = 0; mt < 4; ++mt)
        #pragma unroll
        for (int nt = 0; nt < 2; ++nt)
            acc[mt][nt] = (f32x4){0.f, 0.f, 0.f, 0.f};
    #pragma unroll
    for (int k = 0; k < 8; ++k) {
        bf16x8 a[4], bb[2];
        #pragma unroll
        for (int mt = 0; mt < 4; ++mt) {
            int t = mt * 16 + lrow;
            int slot = (k * 4 + lk) ^ (t & 7);
            a[mt] = *(const bf16x8*)(lds + t * 512 + (slot << 4));
        }
        #pragma unroll
        for (int nt = 0; nt < 2; ++nt) {
            int j = j0 + nt * 16 + lrow;
            bb[nt] = *(const bf16x8*)((const unsigned char*)wo + (size_t)j * 512 + k * 64 + lk * 16);
        }
        #pragma unroll
        for (int mt = 0; mt < 4; ++mt)
            #pragma unroll
            for (int nt = 0; nt < 2; ++nt)
                acc[mt][nt] = __builtin_amdgcn_mfma_f32_16x16x32_bf16(a[mt], bb[nt], acc[mt][nt], 0, 0, 0);
    }
    float bias[2];
    #pragma unroll
    for (int nt = 0; nt < 2; ++nt) bias[nt] = b_out[j0 + nt * 16 + lrow];
    __syncthreads();   // out2 tile dead; reuse LDS for fp32 y (two 128-col halves)

    const size_t obase = ((size_t)b * 256) * 16384 + (size_t)(iw * 8) * 128 + ih * 8;
    #pragma unroll
    for (int half = 0; half < 2; ++half) {
        if ((wave >> 2) == half) {
            int jl = (wave & 3) * 32;
            #pragma unroll
            for (int mt = 0; mt < 4; ++mt)
                #pragma unroll
                for (int nt = 0; nt < 2; ++nt)
                    #pragma unroll
                    for (int i = 0; i < 4; ++i) {
                        int t = mt * 16 + lk * 4 + i;
                        int el = jl + nt * 16 + lrow;      // 0..127
                        int sl = (el >> 2) ^ (t & 7);
                        *(float*)(lds + t * 512 + (sl << 4) + (el & 3) * 4) = acc[mt][nt][i] + bias[nt];
                    }
        }
        __syncthreads();
        #pragma unroll
        for (int it = 0; it < 2; ++it) {
            int idx = it * 512 + tid;              // 0..1023
            int el = idx >> 3, sp = idx & 7;       // el 0..127
            float vals[8];
            #pragma unroll
            for (int rp = 0; rp < 8; ++rp) {
                int t = rp * 8 + sp;
                int sl = (el >> 2) ^ (t & 7);
                vals[rp] = *(const float*)(lds + t * 512 + (sl << 4) + (el & 3) * 4);
            }
            float* po = out + obase + (size_t)(half * 128 + el) * 16384 + sp * 128;
            *(float4*)po       = make_float4(vals[0], vals[1], vals[2], vals[3]);
            *(float4*)(po + 4) = make_float4(vals[4], vals[5], vals[6], vals[7]);
        }
        __syncthreads();
    }
}

// ================= PATH B (fallback, proven round-2 fused k1) =================
__global__ __launch_bounds__(512, 4) void qkv_attn_kernel(
        const float* __restrict__ x, const unsigned short* __restrict__ wq,
        unsigned short* __restrict__ o_ws) {
    __shared__ unsigned char lds[65536];
    const int tid = threadIdx.x;
    const int bid = blockIdx.x;
    const int rpair = bid & 3;
    const int iwp   = (bid >> 2) & 7;
    const int ih    = (bid >> 5) & 15;
    const int b     = bid >> 9;
    const int r0 = rpair * 2;
    const float* xb2 = x + (size_t)b * 4194304 + (size_t)(ih * 8 + r0) * 128 + iwp * 16;

    #pragma unroll
    for (int it = 0; it < 4; ++it) {
        int idx = it * 512 + tid;
        int c_lo = idx & 7;
        int q4   = (idx >> 3) & 3;
        int c_hi = (idx >> 5) & 31;
        int rl   = idx >> 10;
        int c = c_hi * 8 + c_lo;
        float4 v = *(const float4*)(xb2 + (size_t)c * 16384 + rl * 128 + q4 * 4);
        #pragma unroll
        for (int j = 0; j < 4; ++j) {
            int t = rl * 16 + q4 * 4 + j;
            int slot = (c >> 3) ^ (t & 7);
            float f = (j == 0) ? v.x : (j == 1) ? v.y : (j == 2) ? v.z : v.w;
            *(unsigned short*)(lds + 49152 + t * 512 + (slot << 4) + (c & 7) * 2) = f2bf(f);
        }
    }
    __syncthreads();

    const int lane = tid & 63;
    const int wave = tid >> 6;
    const int lrow = lane & 15;
    const int lk   = lane >> 4;

    {
        const int j0 = wave * 96;
        f32x4 acc[2][6];
        #pragma unroll
        for (int mt = 0; mt < 2; ++mt)
            #pragma unroll
            for (int nt = 0; nt < 6; ++nt)
                acc[mt][nt] = (f32x4){0.f, 0.f, 0.f, 0.f};
        #pragma unroll
        for (int k = 0; k < 8; ++k) {
            bf16x8 a[2], bb[6];
            #pragma unroll
            for (int mt = 0; mt < 2; ++mt) {
                int t = mt * 16 + lrow;
                int slot = (k * 4 + lk) ^ (t & 7);
                a[mt] = *(const bf16x8*)(lds + 49152 + t * 512 + (slot << 4));
            }
            #pragma unroll
            for (int nt = 0; nt < 6; ++nt) {
                int j = j0 + nt * 16 + lrow;
                bb[nt] = *(const bf16x8*)((const unsigned char*)wq + (size_t)j * 512 + k * 64 + lk * 16);
            }
            #pragma unroll
            for (int mt = 0; mt < 2; ++mt)
                #pragma unroll
                for (int nt = 0; nt < 6; ++nt)
                    acc[mt][nt] = __builtin_amdgcn_mfma_f32_16x16x32_bf16(a[mt], bb[nt], acc[mt][nt], 0, 0, 0);
        }
        #pragma unroll
        for (int mt = 0; mt < 2; ++mt)
            #pragma unroll
            for (int nt = 0; nt < 6; ++nt)
                #pragma unroll
                for (int i = 0; i < 4; ++i) {
                    int t = mt * 16 + lk * 4 + i;
                    int ch = j0 + nt * 16 + lrow;
                    int slot = (ch >> 3) ^ (t & 7);
                    *(unsigned short*)(lds + t * 1536 + (slot << 4) + (ch & 7) * 2) = f2bf(acc[mt][nt][i]);
                }
    }
    __syncthreads();

    {
        const int t  = tid >> 4;
        const int h  = (tid >> 1) & 7;
        const int hf = tid & 1;
        const int tx = t & 7;
        const unsigned char* row = lds + t * 1536;
        float q[16];
        #pragma unroll
        for (int jj = 0; jj < 2; ++jj) {
            int slot = (h * 4 + hf * 2 + jj) ^ tx;
            bf16x8 v = *(const bf16x8*)(row + (slot << 4));
            #pragma unroll
            for (int e = 0; e < 8; ++e) q[jj * 8 + e] = bf2f((unsigned short)v[e]);
        }
        float dots[8];
        #pragma unroll
        for (int g = 0; g < 8; ++g) {
            float acc = 0.f;
            #pragma unroll
            for (int jj = 0; jj < 2; ++jj) {
                int slot = (32 + g * 4 + hf * 2 + jj) ^ tx;
                bf16x8 v = *(const bf16x8*)(row + (slot << 4));
                #pragma unroll
                for (int e = 0; e < 8; ++e) acc += q[jj * 8 + e] * bf2f((unsigned short)v[e]);
            }
            dots[g] = acc;
        }
        #pragma unroll
        for (int g = 0; g < 8; ++g)
            dots[g] = (dots[g] + __shfl_xor(dots[g], 1, 64)) * SCALE;
        float mx = dots[0];
        #pragma unroll
        for (int g = 1; g < 8; ++g) mx = fmaxf(mx, dots[g]);
        float sum = 0.f;
        #pragma unroll
        for (int g = 0; g < 8; ++g) { dots[g] = __expf(dots[g] - mx); sum += dots[g]; }
        float inv = 1.f / sum;
        float o[16];
        #pragma unroll
        for (int d = 0; d < 16; ++d) o[d] = 0.f;
        #pragma unroll
        for (int g = 0; g < 8; ++g) {
            float p = dots[g] * inv;
            #pragma unroll
            for (int jj = 0; jj < 2; ++jj) {
                int slot = (64 + g * 4 + hf * 2 + jj) ^ tx;
                bf16x8 v = *(const bf16x8*)(row + (slot << 4));
                #pragma unroll
                for (int e = 0; e < 8; ++e) o[jj * 8 + e] += p * bf2f((unsigned short)v[e]);
            }
        }
        const int rl = t >> 4, sg = t & 15;
        const int win = b * 256 + ih * 16 + iwp * 2 + (sg >> 3);
        const int r = r0 + rl, s = sg & 7;
        unsigned short* dst = o_ws + ((size_t)win * 64 + h * 8 + r) * 256 + s * 32 + hf * 16;
        #pragma unroll
        for (int jj = 0; jj < 2; ++jj) {
            bf16x8 pk;
            #pragma unroll
            for (int e = 0; e < 8; ++e) pk[e] = (short)f2bf(o[jj * 8 + e]);
            *(bf16x8*)(dst + jj * 8) = pk;
        }
    }
}

extern "C" void kernel_launch(void* const* d_in, const int* in_sizes, int n_in,
                              void* d_out, int out_size, void* d_ws, size_t ws_size,
                              hipStream_t stream) {
    const float* x     = (const float*)d_in[0];
    const float* w_qkv = (const float*)d_in[1];
    const float* w_out = (const float*)d_in[2];
    const float* b_out = (const float*)d_in[3];
    float* out = (float*)d_out;

    const size_t QKV_BYTES = 201326592;   // 131072 x 768 x 2
    const size_t O_BYTES   = 67108864;    // 2048 x 64 x 256 x 2

    if (ws_size >= QKV_BYTES + O_BYTES + 786432) {
        // Path A: split pipeline
        unsigned short* qkv_ws = (unsigned short*)d_ws;
        unsigned short* o_ws   = (unsigned short*)((char*)d_ws + QKV_BYTES);
        unsigned short* wq     = (unsigned short*)((char*)d_ws + QKV_BYTES + O_BYTES);
        unsigned short* wo     = wq + 196608;
        wconv_kernel<<<dim3(1024), dim3(256), 0, stream>>>(w_qkv, w_out, wq, wo);
        qkv_gemm_kernel<<<dim3(2048), dim3(512), 0, stream>>>(x, wq, qkv_ws);
        attn_kernel<<<dim3(4096), dim3(512), 0, stream>>>(qkv_ws, o_ws);
        outproj_kernel<<<dim3(2048), dim3(512), 0, stream>>>(o_ws, wo, b_out, out);
    } else {
        // Path B: fused fallback (round-2 proven)
        unsigned short* o_ws = (unsigned short*)d_ws;
        unsigned short* wq   = (unsigned short*)((char*)d_ws + O_BYTES);
        unsigned short* wo   = wq + 196608;
        wconv_kernel<<<dim3(1024), dim3(256), 0, stream>>>(w_qkv, w_out, wq, wo);
        qkv_attn_kernel<<<dim3(4096), dim3(512), 0, stream>>>(x, wq, o_ws);
        outproj_kernel<<<dim3(2048), dim3(512), 0, stream>>>(o_ws, wo, b_out, out);
    }
}